// Round 11
// baseline (1132.267 us; speedup 1.0000x reference)
//
#include <hip/hip_runtime.h>

// LabelizerNet: avg-pool(6,2) -> RGB->HSV -> yellow/blue mask -> per-panel max/min
// Input : states (N, 3, 84, 84) f32   (N = 4096)
// Output: labels (N, 6) f32  [yellow panels 0..2, blue panels 0..2]
//
// Round 11: quarter-image blocks (24 rows, 24.6 KB LDS) staged entirely via
// global_load_lds (round 10's proven lever) -> 5 blocks/CU of staggered
// stage/compute for deeper DMA queues. Finalize folded into the pool kernel
// via per-image arrival counters. Math bit-identical to rounds 3-10.

#define CH_ELEMS 7056              // 84*84
#define IMG_F4   5292              // 3*7056/4
#define CH_F4    1764              // 7056/4
#define ROW_F4   21                // 84/4
#define Q_F4     504               // 24 rows * 21 f4 staged per channel
#define SLOT_F4  512               // channel slot in LDS (8-f4 overrun gap)
#define LDS_F4   1536              // 3 * SLOT_F4 = 24576 B
#define ROW_STR  84                // floats per row in LDS

__device__ __forceinline__ void gl_lds16(const float4* g, float4* l) {
    __builtin_amdgcn_global_load_lds(
        (const __attribute__((address_space(1))) void*)(uintptr_t)(const void*)g,
        (__attribute__((address_space(3))) void*)(uintptr_t)(void*)l,
        16, 0, 0);
}

__global__ __launch_bounds__(256, 5)
void pool_mask_kernel(const float* __restrict__ in, unsigned* __restrict__ ws,
                      float* __restrict__ out, int N) {
    __shared__ float4 s4[LDS_F4];          // 24576 B

    const int tid = threadIdx.x;
    const int img = blockIdx.x >> 2;
    const int q   = blockIdx.x & 3;        // quarter: pooled rows 10q..10q+9
    const int R0f4 = q * 20 * ROW_F4;      // input row 20q, in f4 units (420q)
    const bool lastimg = (img == N - 1);

    // ---- stage 3 x 504 f4 (24 rows/channel) entirely via direct-to-LDS DMA ----
    const float4* src = (const float4*)in + (size_t)img * IMG_F4 + R0f4;
    const int wid = tid >> 6, lane = tid & 63;
    #pragma unroll
    for (int c = 0; c < 3; ++c) {
        const float4* sc = src + c * CH_F4;
        float4* dc = s4 + c * SLOT_F4;
        #pragma unroll
        for (int k = wid; k < 8; k += 4) {     // 8 chunks x 64 f4 (8-f4 overrun into slot gap)
            int i = k * 64 + lane;
            int gi = i;
            if (lastimg) gi = min(R0f4 + i, CH_F4 - 1) - R0f4;  // stay in-buffer
            gl_lds16(sc + gi, dc + i);
        }
    }
    __syncthreads();   // drains vmcnt (DMA writes to LDS)

    // ---- compute: thread = (pooled row pr 0..9, pair-column xp 0..19) ----
    unsigned my = 0u;
    if (tid < 200) {
        const int pr = tid / 20;             // pooled row within quarter
        const int xp = tid - pr * 20;        // 0..19
        const int x0 = 2 * xp, x1 = 2 * xp + 1;
        const float* sf = (const float*)s4;
        const int lbase = (2 * pr) * ROW_STR + 4 * xp;   // local input row 2pr

        float t0[3], t1[3];
        #pragma unroll
        for (int c = 0; c < 3; ++c) {
            float P0[3], P1[3];
            #pragma unroll
            for (int j = 0; j < 3; ++j) {    // row-pairs: rows 2pr+2j, 2pr+2j+1
                const float* rbase = sf + c * (4 * SLOT_F4) + lbase + (2 * j) * ROW_STR;
                const float4* ra = (const float4*)rbase;
                const float4* rb = (const float4*)(rbase + ROW_STR);
                float4 qa0 = ra[0], qa1 = ra[1];
                float4 qb0 = rb[0], qb1 = rb[1];
                float a01 = qa0.x + qa0.y, a23 = qa0.z + qa0.w;
                float a45 = qa1.x + qa1.y, a67 = qa1.z + qa1.w;
                float rsa0 = (a01 + a23) + a45;      // rs[2j],  window x0
                float rsa1 = (a23 + a45) + a67;      // rs[2j],  window x1
                float b01 = qb0.x + qb0.y, b23 = qb0.z + qb0.w;
                float b45 = qb1.x + qb1.y, b67 = qb1.z + qb1.w;
                float rsb0 = (b01 + b23) + b45;      // rs[2j+1], window x0
                float rsb1 = (b23 + b45) + b67;      // rs[2j+1], window x1
                P0[j] = rsa0 + rsb0;
                P1[j] = rsa1 + rsb1;
            }
            t0[c] = (P0[0] + P0[1]) + P0[2];         // == ((rs0+rs1)+(rs2+rs3))+(rs4+rs5)
            t1[c] = (P1[0] + P1[1]) + P1[2];
        }

        #pragma unroll
        for (int e = 0; e < 2; ++e) {
            float r = ((e == 0) ? t0[0] : t1[0]) / 36.0f;
            float g = ((e == 0) ? t0[1] : t1[1]) / 36.0f;
            float b = ((e == 0) ? t0[2] : t1[2]) / 36.0f;

            float maxc = fmaxf(r, fmaxf(g, b));
            float minc = fminf(r, fminf(g, b));
            float delta = maxc - minc;
            float s = (maxc == 0.0f) ? 0.0f : delta / maxc;
            float v = maxc;
            float h = 0.0f;
            if (delta != 0.0f) {
                float rc = (maxc - r) / delta;
                float gc = (maxc - g) / delta;
                float bc = (maxc - b) / delta;
                float hh = (r == maxc) ? (bc - gc)
                         : ((g == maxc) ? (2.0f + rc - bc)
                                        : (4.0f + gc - rc));
                h = hh / 6.0f;           // in (-1/6, 5/6); floor-mod 1:
                if (h < 0.0f) h += 1.0f;
            }
            bool satval = (s > 0.5f) && (v > 0.5f);
            int m = 0;
            if (satval && h >= 0.1f && h <= 0.2f) m = 1;
            else if (satval && h >= 0.55f && h <= 0.7f) m = -1;

            int x = (e == 0) ? x0 : x1;
            if (x < 39) {                 // col 39 excluded (40//3*3 == 39)
                int pan = x / 13;         // 0..2
                unsigned bit = (m > 0) ? 1u : (m < 0) ? 2u : 4u;
                my |= bit << (3 * pan);
            }
        }
    }

    // wave OR-reduce -> one device atomic per wave
    #pragma unroll
    for (int off = 32; off > 0; off >>= 1) my |= __shfl_xor(my, off);
    if ((tid & 63) == 0 && my) atomicOr(&ws[img], my);
    __syncthreads();

    // last of the image's 4 quarter-blocks writes the 6 outputs
    if (tid == 0) {
        __threadfence();
        unsigned old = atomicAdd(&ws[N + img], 1u);
        if (old == 3u) {
            unsigned mask = atomicOr(&ws[img], 0u);   // device-scope read
            #pragma unroll
            for (int j = 0; j < 6; ++j) {
                int pan = (j < 3) ? j : j - 3;
                unsigned w = mask >> (3 * pan);
                bool anyY = w & 1u;
                bool anyB = (w >> 1) & 1u;
                bool anyZ = (w >> 2) & 1u;
                float val;
                if (j < 3) val = anyY ? 1.0f : (anyZ ? 0.0f : -1.0f);   // max(panel)
                else       val = anyB ? 1.0f : (anyZ ? 0.0f : -1.0f);   // -min(panel)
                out[(size_t)img * 6 + j] = val;
            }
        }
    }
}

extern "C" void kernel_launch(void* const* d_in, const int* in_sizes, int n_in,
                              void* d_out, int out_size, void* d_ws, size_t ws_size,
                              hipStream_t stream) {
    const float* states = (const float*)d_in[0];
    float* out = (float*)d_out;
    unsigned* ws = (unsigned*)d_ws;
    int N = in_sizes[0] / (3 * CH_ELEMS);   // 4096

    hipMemsetAsync(ws, 0, (size_t)(2 * N) * sizeof(unsigned), stream);
    pool_mask_kernel<<<4 * N, 256, 0, stream>>>(states, ws, out, N);
}

// Round 12
// 811.140 us; speedup vs baseline: 1.3959x; 1.3959x over previous
//
#include <hip/hip_runtime.h>

// LabelizerNet: avg-pool(6,2) -> RGB->HSV -> yellow/blue mask -> per-panel max/min
// Input : states (N, 3, 84, 84) f32   (N = 4096)
// Output: labels (N, 6) f32  [yellow panels 0..2, blue panels 0..2]
//
// Round 12: round-11 quarter-image DMA structure WITHOUT the VGPR clamp
// (round 11's launch_bounds(256,5) forced VGPR=48 -> 755 MB scratch spill).
// Plain launch_bounds(256): VGPR free (~80), occupancy LDS-governed at
// 6 blocks/CU (24.6 KB each) -> 2x round 10's stage/compute stagger.
// Math bit-identical to rounds 3-11.

#define CH_ELEMS 7056              // 84*84
#define IMG_F4   5292              // 3*7056/4
#define CH_F4    1764              // 7056/4
#define ROW_F4   21                // 84/4
#define Q_F4     504               // 24 rows * 21 f4 staged per channel
#define SLOT_F4  512               // channel slot in LDS (8-f4 overrun gap)
#define LDS_F4   1536              // 3 * SLOT_F4 = 24576 B
#define ROW_STR  84                // floats per row in LDS

__device__ __forceinline__ void gl_lds16(const float4* g, float4* l) {
    __builtin_amdgcn_global_load_lds(
        (const __attribute__((address_space(1))) void*)(uintptr_t)(const void*)g,
        (__attribute__((address_space(3))) void*)(uintptr_t)(void*)l,
        16, 0, 0);
}

__global__ __launch_bounds__(256)
void pool_mask_kernel(const float* __restrict__ in, unsigned* __restrict__ ws,
                      float* __restrict__ out, int N) {
    __shared__ float4 s4[LDS_F4];          // 24576 B

    const int tid = threadIdx.x;
    const int img = blockIdx.x >> 2;
    const int q   = blockIdx.x & 3;        // quarter: pooled rows 10q..10q+9
    const int R0f4 = q * 20 * ROW_F4;      // input row 20q, in f4 units

    // ---- stage 3 x 504 f4 (24 rows/channel) entirely via direct-to-LDS DMA.
    // Source index clamped to the staged range (per-lane source is allowed;
    // LDS dest stays lane-linear). The 8-f4 overrun lands in the slot gap.
    const float4* src = (const float4*)in + (size_t)img * IMG_F4 + R0f4;
    const int wid = tid >> 6, lane = tid & 63;
    #pragma unroll
    for (int c = 0; c < 3; ++c) {
        const float4* sc = src + c * CH_F4;
        float4* dc = s4 + c * SLOT_F4;
        #pragma unroll
        for (int k = wid; k < 8; k += 4) {     // 8 chunks x 64 f4 = 512
            int i = k * 64 + lane;
            int gi = min(i, Q_F4 - 1);         // no OOB reads, ever
            gl_lds16(sc + gi, dc + i);
        }
    }
    __syncthreads();   // drains vmcnt (DMA writes to LDS)

    // ---- compute: thread = (pooled row pr 0..9, pair-column xp 0..19) ----
    unsigned my = 0u;
    if (tid < 200) {
        const int pr = tid / 20;             // pooled row within quarter
        const int xp = tid - pr * 20;        // 0..19
        const int x0 = 2 * xp, x1 = 2 * xp + 1;
        const float* sf = (const float*)s4;
        const int lbase = (2 * pr) * ROW_STR + 4 * xp;   // local input row 2pr

        float t0[3], t1[3];
        #pragma unroll
        for (int c = 0; c < 3; ++c) {
            float P0[3], P1[3];
            #pragma unroll
            for (int j = 0; j < 3; ++j) {    // row-pairs: rows 2pr+2j, 2pr+2j+1
                const float* rbase = sf + c * (4 * SLOT_F4) + lbase + (2 * j) * ROW_STR;
                const float4* ra = (const float4*)rbase;
                const float4* rb = (const float4*)(rbase + ROW_STR);
                float4 qa0 = ra[0], qa1 = ra[1];
                float4 qb0 = rb[0], qb1 = rb[1];
                float a01 = qa0.x + qa0.y, a23 = qa0.z + qa0.w;
                float a45 = qa1.x + qa1.y, a67 = qa1.z + qa1.w;
                float rsa0 = (a01 + a23) + a45;      // rs[2j],  window x0
                float rsa1 = (a23 + a45) + a67;      // rs[2j],  window x1
                float b01 = qb0.x + qb0.y, b23 = qb0.z + qb0.w;
                float b45 = qb1.x + qb1.y, b67 = qb1.z + qb1.w;
                float rsb0 = (b01 + b23) + b45;      // rs[2j+1], window x0
                float rsb1 = (b23 + b45) + b67;      // rs[2j+1], window x1
                P0[j] = rsa0 + rsb0;
                P1[j] = rsa1 + rsb1;
            }
            t0[c] = (P0[0] + P0[1]) + P0[2];         // == ((rs0+rs1)+(rs2+rs3))+(rs4+rs5)
            t1[c] = (P1[0] + P1[1]) + P1[2];
        }

        #pragma unroll
        for (int e = 0; e < 2; ++e) {
            float r = ((e == 0) ? t0[0] : t1[0]) / 36.0f;
            float g = ((e == 0) ? t0[1] : t1[1]) / 36.0f;
            float b = ((e == 0) ? t0[2] : t1[2]) / 36.0f;

            float maxc = fmaxf(r, fmaxf(g, b));
            float minc = fminf(r, fminf(g, b));
            float delta = maxc - minc;
            float s = (maxc == 0.0f) ? 0.0f : delta / maxc;
            float v = maxc;
            float h = 0.0f;
            if (delta != 0.0f) {
                float rc = (maxc - r) / delta;
                float gc = (maxc - g) / delta;
                float bc = (maxc - b) / delta;
                float hh = (r == maxc) ? (bc - gc)
                         : ((g == maxc) ? (2.0f + rc - bc)
                                        : (4.0f + gc - rc));
                h = hh / 6.0f;           // in (-1/6, 5/6); floor-mod 1:
                if (h < 0.0f) h += 1.0f;
            }
            bool satval = (s > 0.5f) && (v > 0.5f);
            int m = 0;
            if (satval && h >= 0.1f && h <= 0.2f) m = 1;
            else if (satval && h >= 0.55f && h <= 0.7f) m = -1;

            int x = (e == 0) ? x0 : x1;
            if (x < 39) {                 // col 39 excluded (40//3*3 == 39)
                int pan = x / 13;         // 0..2
                unsigned bit = (m > 0) ? 1u : (m < 0) ? 2u : 4u;
                my |= bit << (3 * pan);
            }
        }
    }

    // wave OR-reduce -> one device atomic per wave
    #pragma unroll
    for (int off = 32; off > 0; off >>= 1) my |= __shfl_xor(my, off);
    if ((tid & 63) == 0 && my) atomicOr(&ws[img], my);
    __syncthreads();

    // last of the image's 4 quarter-blocks writes the 6 outputs
    if (tid == 0) {
        __threadfence();
        unsigned old = atomicAdd(&ws[N + img], 1u);
        if (old == 3u) {
            unsigned mask = atomicOr(&ws[img], 0u);   // device-scope read
            #pragma unroll
            for (int j = 0; j < 6; ++j) {
                int pan = (j < 3) ? j : j - 3;
                unsigned w = mask >> (3 * pan);
                bool anyY = w & 1u;
                bool anyB = (w >> 1) & 1u;
                bool anyZ = (w >> 2) & 1u;
                float val;
                if (j < 3) val = anyY ? 1.0f : (anyZ ? 0.0f : -1.0f);   // max(panel)
                else       val = anyB ? 1.0f : (anyZ ? 0.0f : -1.0f);   // -min(panel)
                out[(size_t)img * 6 + j] = val;
            }
        }
    }
}

extern "C" void kernel_launch(void* const* d_in, const int* in_sizes, int n_in,
                              void* d_out, int out_size, void* d_ws, size_t ws_size,
                              hipStream_t stream) {
    const float* states = (const float*)d_in[0];
    float* out = (float*)d_out;
    unsigned* ws = (unsigned*)d_ws;
    int N = in_sizes[0] / (3 * CH_ELEMS);   // 4096

    hipMemsetAsync(ws, 0, (size_t)(2 * N) * sizeof(unsigned), stream);
    pool_mask_kernel<<<4 * N, 256, 0, stream>>>(states, ws, out, N);
}

// Round 13
// 90.094 us; speedup vs baseline: 12.5676x; 9.0032x over previous
//
#include <hip/hip_runtime.h>

// LabelizerNet: avg-pool(6,2) -> RGB->HSV -> yellow/blue mask -> per-panel max/min
// Input : states (N, 3, 84, 84) f32   (N = 4096)
// Output: labels (N, 6) f32  [yellow panels 0..2, blue panels 0..2]
//
// Round 13: quarter-image blocks (24 rows, 24.6 KB LDS -> 6 blocks/CU), staging
// 100% global_load_lds DMA (round 10's proven lever). NO fused finalize:
// round 11/12's per-block __threadfence() = per-XCD L2 writeback x 16384
// blocks = the 10x regression. Separate tiny finalize kernel (round 10's).
// Math bit-identical to all passing rounds.

#define CH_ELEMS 7056              // 84*84
#define IMG_F4   5292              // 3*7056/4
#define CH_F4    1764              // 7056/4
#define ROW_F4   21                // 84/4
#define Q_F4     504               // 24 rows * 21 f4 staged per channel
#define SLOT_F4  512               // channel slot in LDS (8-f4 overrun gap)
#define LDS_F4   1536              // 3 * SLOT_F4 = 24576 B
#define ROW_STR  84                // floats per row in LDS

__device__ __forceinline__ void gl_lds16(const float4* g, float4* l) {
    __builtin_amdgcn_global_load_lds(
        (const __attribute__((address_space(1))) void*)(uintptr_t)(const void*)g,
        (__attribute__((address_space(3))) void*)(uintptr_t)(void*)l,
        16, 0, 0);
}

__global__ __launch_bounds__(256)
void pool_mask_kernel(const float* __restrict__ in, unsigned* __restrict__ ws) {
    __shared__ float4 s4[LDS_F4];          // 24576 B

    const int tid = threadIdx.x;
    const int img = blockIdx.x >> 2;
    const int q   = blockIdx.x & 3;        // quarter: pooled rows 10q..10q+9
    const int R0f4 = q * 20 * ROW_F4;      // input row 20q, in f4 units

    // ---- stage 3 x 504 f4 (24 rows/channel) entirely via direct-to-LDS DMA.
    // Per-lane source index is allowed (clamped to staged range: no OOB reads);
    // LDS dest stays lane-linear. The 8-f4 overrun lands in the slot gap.
    const float4* src = (const float4*)in + (size_t)img * IMG_F4 + R0f4;
    const int wid = tid >> 6, lane = tid & 63;
    #pragma unroll
    for (int c = 0; c < 3; ++c) {
        const float4* sc = src + c * CH_F4;
        float4* dc = s4 + c * SLOT_F4;
        #pragma unroll
        for (int k = wid; k < 8; k += 4) {     // 8 chunks x 64 f4 = 512
            int i = k * 64 + lane;
            int gi = min(i, Q_F4 - 1);         // no OOB reads, ever
            gl_lds16(sc + gi, dc + i);
        }
    }
    __syncthreads();   // drains vmcnt (DMA writes to LDS)

    // ---- compute: thread = (pooled row pr 0..9, pair-column xp 0..19) ----
    unsigned my = 0u;
    if (tid < 200) {
        const int pr = tid / 20;             // pooled row within quarter
        const int xp = tid - pr * 20;        // 0..19
        const int x0 = 2 * xp, x1 = 2 * xp + 1;
        const float* sf = (const float*)s4;
        const int lbase = (2 * pr) * ROW_STR + 4 * xp;   // local input row 2pr

        float t0[3], t1[3];
        #pragma unroll
        for (int c = 0; c < 3; ++c) {
            float P0[3], P1[3];
            #pragma unroll
            for (int j = 0; j < 3; ++j) {    // row-pairs: rows 2pr+2j, 2pr+2j+1
                const float* rbase = sf + c * (4 * SLOT_F4) + lbase + (2 * j) * ROW_STR;
                const float4* ra = (const float4*)rbase;
                const float4* rb = (const float4*)(rbase + ROW_STR);
                float4 qa0 = ra[0], qa1 = ra[1];
                float4 qb0 = rb[0], qb1 = rb[1];
                float a01 = qa0.x + qa0.y, a23 = qa0.z + qa0.w;
                float a45 = qa1.x + qa1.y, a67 = qa1.z + qa1.w;
                float rsa0 = (a01 + a23) + a45;      // rs[2j],  window x0
                float rsa1 = (a23 + a45) + a67;      // rs[2j],  window x1
                float b01 = qb0.x + qb0.y, b23 = qb0.z + qb0.w;
                float b45 = qb1.x + qb1.y, b67 = qb1.z + qb1.w;
                float rsb0 = (b01 + b23) + b45;      // rs[2j+1], window x0
                float rsb1 = (b23 + b45) + b67;      // rs[2j+1], window x1
                P0[j] = rsa0 + rsb0;
                P1[j] = rsa1 + rsb1;
            }
            t0[c] = (P0[0] + P0[1]) + P0[2];         // == ((rs0+rs1)+(rs2+rs3))+(rs4+rs5)
            t1[c] = (P1[0] + P1[1]) + P1[2];
        }

        #pragma unroll
        for (int e = 0; e < 2; ++e) {
            float r = ((e == 0) ? t0[0] : t1[0]) / 36.0f;
            float g = ((e == 0) ? t0[1] : t1[1]) / 36.0f;
            float b = ((e == 0) ? t0[2] : t1[2]) / 36.0f;

            float maxc = fmaxf(r, fmaxf(g, b));
            float minc = fminf(r, fminf(g, b));
            float delta = maxc - minc;
            float s = (maxc == 0.0f) ? 0.0f : delta / maxc;
            float v = maxc;
            float h = 0.0f;
            if (delta != 0.0f) {
                float rc = (maxc - r) / delta;
                float gc = (maxc - g) / delta;
                float bc = (maxc - b) / delta;
                float hh = (r == maxc) ? (bc - gc)
                         : ((g == maxc) ? (2.0f + rc - bc)
                                        : (4.0f + gc - rc));
                h = hh / 6.0f;           // in (-1/6, 5/6); floor-mod 1:
                if (h < 0.0f) h += 1.0f;
            }
            bool satval = (s > 0.5f) && (v > 0.5f);
            int m = 0;
            if (satval && h >= 0.1f && h <= 0.2f) m = 1;
            else if (satval && h >= 0.55f && h <= 0.7f) m = -1;

            int x = (e == 0) ? x0 : x1;
            if (x < 39) {                 // col 39 excluded (40//3*3 == 39)
                int pan = x / 13;         // 0..2
                unsigned bit = (m > 0) ? 1u : (m < 0) ? 2u : 4u;
                my |= bit << (3 * pan);
            }
        }
    }

    // wave OR-reduce -> one device atomic per wave
    #pragma unroll
    for (int off = 32; off > 0; off >>= 1) my |= __shfl_xor(my, off);
    if ((tid & 63) == 0 && my) atomicOr(&ws[img], my);
}

__global__ __launch_bounds__(256)
void finalize_kernel(const unsigned* __restrict__ ws, float* __restrict__ out, int N) {
    int i = blockIdx.x * 256 + threadIdx.x;
    if (i < N * 6) {
        int img = i / 6;
        int j = i - img * 6;
        int pan = (j < 3) ? j : j - 3;
        unsigned w = ws[img] >> (3 * pan);
        bool anyY = w & 1u;
        bool anyB = (w >> 1) & 1u;
        bool anyZ = (w >> 2) & 1u;
        float val;
        if (j < 3) val = anyY ? 1.0f : (anyZ ? 0.0f : -1.0f);   // max(panel)
        else       val = anyB ? 1.0f : (anyZ ? 0.0f : -1.0f);   // -min(panel)
        out[i] = val;
    }
}

extern "C" void kernel_launch(void* const* d_in, const int* in_sizes, int n_in,
                              void* d_out, int out_size, void* d_ws, size_t ws_size,
                              hipStream_t stream) {
    const float* states = (const float*)d_in[0];
    float* out = (float*)d_out;
    unsigned* ws = (unsigned*)d_ws;
    int N = in_sizes[0] / (3 * CH_ELEMS);   // 4096

    hipMemsetAsync(ws, 0, (size_t)N * sizeof(unsigned), stream);
    pool_mask_kernel<<<4 * N, 256, 0, stream>>>(states, ws);
    int blocks2 = (N * 6 + 255) / 256;
    finalize_kernel<<<blocks2, 256, 0, stream>>>(ws, out, N);
}

// Round 14
// 73.281 us; speedup vs baseline: 15.4511x; 1.2294x over previous
//
#include <hip/hip_runtime.h>

// LabelizerNet: avg-pool(6,2) -> RGB->HSV -> yellow/blue mask -> per-panel max/min
// Input : states (N, 3, 84, 84) f32   (N = 4096)
// Output: labels (N, 6) f32  [yellow panels 0..2, blue panels 0..2]
//
// Round 14: fused single kernel, block = one image. Quarter-tiles (24 rows)
// double-buffered in LDS (2 x 24 KB -> 3 blocks/CU), staged 100% via
// global_load_lds with a COUNTED vmcnt pipeline: stage Q(q+1) issues before
// compute Q(q); s_waitcnt vmcnt(6) (6 DMA per wave per stage) + raw s_barrier
// so prefetch loads stay in flight across the barrier (never drain to 0 in
// the loop). In-block LDS reduce -> direct output write (no ws / memset /
// finalize launches, no device-scope fences). Math bit-identical to r3-r13.

#define CH_ELEMS 7056              // 84*84
#define IMG_F4   5292              // 3*7056/4
#define CH_F4    1764              // 7056/4
#define ROW_F4   21                // 84/4
#define Q_F4     504               // 24 rows * 21 f4 staged per channel
#define SLOT_F4  512               // channel slot in LDS (8-f4 overrun gap)
#define BUF_F4   1536              // 3 * SLOT_F4 per buffer
#define ROW_STR  84                // floats per row in LDS

__device__ __forceinline__ void gl_lds16(const float4* g, float4* l) {
    __builtin_amdgcn_global_load_lds(
        (const __attribute__((address_space(1))) void*)(uintptr_t)(const void*)g,
        (__attribute__((address_space(3))) void*)(uintptr_t)(void*)l,
        16, 0, 0);
}

__global__ __launch_bounds__(256)
void labelizer_fused(const float* __restrict__ in, float* __restrict__ out) {
    __shared__ float4 s4[2 * BUF_F4];      // 49152 B
    __shared__ unsigned bmask;

    const int tid = threadIdx.x;
    const int img = blockIdx.x;
    const int wid = tid >> 6, lane = tid & 63;
    if (tid == 0) bmask = 0u;

    const float4* base = (const float4*)in + (size_t)img * IMG_F4;
    unsigned my = 0u;

    // ---- stage quarter q (input rows 20q..20q+23) into buffer b: 6 DMA/wave ----
    auto stage = [&](int q, int b) {
        const float4* sq = base + q * 20 * ROW_F4;
        float4* db = s4 + b * BUF_F4;
        #pragma unroll
        for (int c = 0; c < 3; ++c) {
            const float4* sc = sq + c * CH_F4;
            float4* dc = db + c * SLOT_F4;
            #pragma unroll
            for (int k = 0; k < 2; ++k) {
                int i = (wid + 4 * k) * 64 + lane;       // 8 chunks x 64 f4
                gl_lds16(sc + min(i, Q_F4 - 1), dc + i); // src clamped; dest lane-linear
            }
        }
    };

    // ---- compute quarter from buffer b (thread = pooled row pr x pair-col xp) ----
    auto compute = [&](int b) {
        if (tid < 200) {
            const int pr = tid / 20;             // 0..9
            const int xp = tid - pr * 20;        // 0..19
            const int x0 = 2 * xp, x1 = 2 * xp + 1;
            const float* sf = (const float*)(s4 + b * BUF_F4);
            const int lbase = (2 * pr) * ROW_STR + 4 * xp;

            float t0[3], t1[3];
            #pragma unroll
            for (int c = 0; c < 3; ++c) {
                float P0[3], P1[3];
                #pragma unroll
                for (int j = 0; j < 3; ++j) {
                    const float* rbase = sf + c * (4 * SLOT_F4) + lbase + (2 * j) * ROW_STR;
                    const float4* ra = (const float4*)rbase;
                    const float4* rb = (const float4*)(rbase + ROW_STR);
                    float4 qa0 = ra[0], qa1 = ra[1];
                    float4 qb0 = rb[0], qb1 = rb[1];
                    float a01 = qa0.x + qa0.y, a23 = qa0.z + qa0.w;
                    float a45 = qa1.x + qa1.y, a67 = qa1.z + qa1.w;
                    float rsa0 = (a01 + a23) + a45;
                    float rsa1 = (a23 + a45) + a67;
                    float b01 = qb0.x + qb0.y, b23 = qb0.z + qb0.w;
                    float b45 = qb1.x + qb1.y, b67 = qb1.z + qb1.w;
                    float rsb0 = (b01 + b23) + b45;
                    float rsb1 = (b23 + b45) + b67;
                    P0[j] = rsa0 + rsb0;
                    P1[j] = rsa1 + rsb1;
                }
                t0[c] = (P0[0] + P0[1]) + P0[2];     // == ((rs0+rs1)+(rs2+rs3))+(rs4+rs5)
                t1[c] = (P1[0] + P1[1]) + P1[2];
            }

            #pragma unroll
            for (int e = 0; e < 2; ++e) {
                float r = ((e == 0) ? t0[0] : t1[0]) / 36.0f;
                float g = ((e == 0) ? t0[1] : t1[1]) / 36.0f;
                float bb = ((e == 0) ? t0[2] : t1[2]) / 36.0f;

                float maxc = fmaxf(r, fmaxf(g, bb));
                float minc = fminf(r, fminf(g, bb));
                float delta = maxc - minc;
                float s = (maxc == 0.0f) ? 0.0f : delta / maxc;
                float v = maxc;
                float h = 0.0f;
                if (delta != 0.0f) {
                    float rc = (maxc - r) / delta;
                    float gc = (maxc - g) / delta;
                    float bc = (maxc - bb) / delta;
                    float hh = (r == maxc) ? (bc - gc)
                             : ((g == maxc) ? (2.0f + rc - bc)
                                            : (4.0f + gc - rc));
                    h = hh / 6.0f;           // in (-1/6, 5/6); floor-mod 1:
                    if (h < 0.0f) h += 1.0f;
                }
                bool satval = (s > 0.5f) && (v > 0.5f);
                int m = 0;
                if (satval && h >= 0.1f && h <= 0.2f) m = 1;
                else if (satval && h >= 0.55f && h <= 0.7f) m = -1;

                int x = (e == 0) ? x0 : x1;
                if (x < 39) {                 // col 39 excluded (40//3*3 == 39)
                    int pan = x / 13;         // 0..2
                    unsigned bit = (m > 0) ? 1u : (m < 0) ? 2u : 4u;
                    my |= bit << (3 * pan);
                }
            }
        }
    };

    // ---- pipeline: stage Q0; {stage Q(q+1) | wait Q(q) | compute Q(q)} x4 ----
    stage(0, 0);
    __syncthreads();                         // drain prologue (vmcnt 0), publish bmask

    #pragma unroll
    for (int q = 0; q < 4; ++q) {
        if (q < 3) {
            stage(q + 1, (q + 1) & 1);       // 6 more DMA/wave in flight
            asm volatile("s_waitcnt vmcnt(6)" ::: "memory");   // Q(q) landed, Q(q+1) flying
        } else {
            asm volatile("s_waitcnt vmcnt(0)" ::: "memory");   // last tile: full drain
        }
        __builtin_amdgcn_s_barrier();        // all waves' Q(q) visible
        compute(q & 1);
        __builtin_amdgcn_s_barrier();        // all readers done before buf reuse
    }

    // ---- in-block reduce -> direct output write ----
    #pragma unroll
    for (int off = 32; off > 0; off >>= 1) my |= __shfl_xor(my, off);
    if ((tid & 63) == 0 && my) atomicOr(&bmask, my);
    __syncthreads();

    if (tid < 6) {
        int pan = (tid < 3) ? tid : tid - 3;
        unsigned w = bmask >> (3 * pan);
        bool anyY = w & 1u;
        bool anyB = (w >> 1) & 1u;
        bool anyZ = (w >> 2) & 1u;
        float val;
        if (tid < 3) val = anyY ? 1.0f : (anyZ ? 0.0f : -1.0f);   // max(panel)
        else         val = anyB ? 1.0f : (anyZ ? 0.0f : -1.0f);   // -min(panel)
        out[(size_t)img * 6 + tid] = val;
    }
}

extern "C" void kernel_launch(void* const* d_in, const int* in_sizes, int n_in,
                              void* d_out, int out_size, void* d_ws, size_t ws_size,
                              hipStream_t stream) {
    const float* states = (const float*)d_in[0];
    float* out = (float*)d_out;
    int N = in_sizes[0] / (3 * CH_ELEMS);   // 4096
    labelizer_fused<<<N, 256, 0, stream>>>(states, out);
}